// Round 7
// baseline (87.072 us; speedup 1.0000x reference)
//
#include <hip/hip_runtime.h>
#include <hip/hip_bf16.h>
#include <math.h>

// Problem constants
#define BATCH 4
#define TLEN 8192
#define BT 32768      // BATCH*TLEN
#define DIM 512
#define CHUNK 128     // t per scan chunk
#define NCHUNK 64     // TLEN / CHUNK

// score GEMM tile
#define BM 128
#define BN 128
#define BK 32

typedef _Float16 h8 __attribute__((ext_vector_type(8)));
typedef __fp16 fp16x2 __attribute__((ext_vector_type(2)));   // cvt_pkrtz return type
typedef float f4 __attribute__((ext_vector_type(4)));

// fast tanh: 1 - 2/(e^{2z}+1). |err| ~1e-6; saturates correctly at +-1.
__device__ __forceinline__ float fast_tanh(float z) {
    float u = __expf(2.0f * z);
    return 1.0f - __fdividef(2.0f, u + 1.0f);
}

// ---------------------------------------------------------------------------
// Kernel 1: score GEMM with FUSED fp32->fp16 conversion (reg-staged).
// 1024 blocks (256 t-tiles x 4 e-tiles), 256 threads = 4 waves (2x2),
// per-wave 64x64 = 4x4 frags of 16x16x32 f16.
// LDS layout: k-major [4 kg][128 rows][8 halfs] per buffer -- consecutive
// rows = consecutive 16B chunks => conflict-free ds_write AND ds_read.
// Per K-step: LOADR(s+1) fp32 -> COMPUTE(s) [loads land under MFMA] ->
// cvt_pkrtz + ds_write(s+1) -> __syncthreads (VMEM queue already empty).
// Epilogue: fast-tanh + w2 reduce -> spart[be][row] (no atomics).
// ---------------------------------------------------------------------------
__global__ __launch_bounds__(256, 3) void score_mfma_kernel(
    const float* __restrict__ x, const float* __restrict__ W1,
    const float* __restrict__ b1, const float* __restrict__ w2,
    float* __restrict__ spart)
{
    __shared__ _Float16 Als[2][4 * 128 * 8];   // 2 x 8 KB, k-major
    __shared__ _Float16 Bls[2][4 * 128 * 8];   // 2 x 8 KB
    __shared__ float sred[2][BM];              // 1 KB

    // bijective XCD-chunked swizzle over 1024 blocks (1024 % 8 == 0)
    const int orig = blockIdx.x;
    const int wid  = (orig & 7) * 128 + (orig >> 3);
    const int bt = wid >> 2, be = wid & 3;
    const long trow0 = (long)bt * BM;
    const int  ecol0 = be * BN;

    const int tid  = threadIdx.x;
    const int lane = tid & 63;
    const int w    = tid >> 6;       // 0..3
    const int wr   = w >> 1;         // t-half of tile
    const int wc   = w & 1;          // e-half of tile
    const int l15  = lane & 15;
    const int lg   = lane >> 4;      // 0..3

    // staging: lane covers row srow, k-halves [kgb*8, kgb*8+16) of each window
    const int srow = w * 32 + (lane >> 1);   // 0..127
    const int kgb  = (lane & 1) * 2;         // 0 or 2
    const float* gA = x  + (trow0 + srow) * DIM + kgb * 8;
    const float* gB = W1 + (long)(ecol0 + srow) * DIM + kgb * 8;
    const int wof0 = kgb * 1024 + srow * 8;  // halfs; kgroup kgb
    const int wof1 = wof0 + 1024;            // kgroup kgb+1

    // epilogue operands (auto-waited by data dep)
    float b1v[4], w2v[4];
    #pragma unroll
    for (int n = 0; n < 4; ++n) {
        int e = ecol0 + wc * 64 + n * 16 + l15;
        b1v[n] = b1[e];
        w2v[n] = w2[e];
    }

    f4 acc[4][4];
    #pragma unroll
    for (int m = 0; m < 4; ++m)
        #pragma unroll
        for (int n = 0; n < 4; ++n) acc[m][n] = (f4){0.f, 0.f, 0.f, 0.f};

    float4 a0_, a1_, a2_, a3_, b0_, b1_, b2_, b3_;

#define LOADR(k0_) {                                                          \
    a0_ = *(const float4*)(gA + (k0_));                                       \
    a1_ = *(const float4*)(gA + (k0_) + 4);                                   \
    a2_ = *(const float4*)(gA + (k0_) + 8);                                   \
    a3_ = *(const float4*)(gA + (k0_) + 12);                                  \
    b0_ = *(const float4*)(gB + (k0_));                                       \
    b1_ = *(const float4*)(gB + (k0_) + 4);                                   \
    b2_ = *(const float4*)(gB + (k0_) + 8);                                   \
    b3_ = *(const float4*)(gB + (k0_) + 12);                                  }

#define CVTWRITE(bsel_) {                                                     \
    union { h8 v; fp16x2 p[4]; } uA0, uA1, uB0, uB1;                          \
    uA0.p[0] = __builtin_amdgcn_cvt_pkrtz(a0_.x, a0_.y);                      \
    uA0.p[1] = __builtin_amdgcn_cvt_pkrtz(a0_.z, a0_.w);                      \
    uA0.p[2] = __builtin_amdgcn_cvt_pkrtz(a1_.x, a1_.y);                      \
    uA0.p[3] = __builtin_amdgcn_cvt_pkrtz(a1_.z, a1_.w);                      \
    uA1.p[0] = __builtin_amdgcn_cvt_pkrtz(a2_.x, a2_.y);                      \
    uA1.p[1] = __builtin_amdgcn_cvt_pkrtz(a2_.z, a2_.w);                      \
    uA1.p[2] = __builtin_amdgcn_cvt_pkrtz(a3_.x, a3_.y);                      \
    uA1.p[3] = __builtin_amdgcn_cvt_pkrtz(a3_.z, a3_.w);                      \
    uB0.p[0] = __builtin_amdgcn_cvt_pkrtz(b0_.x, b0_.y);                      \
    uB0.p[1] = __builtin_amdgcn_cvt_pkrtz(b0_.z, b0_.w);                      \
    uB0.p[2] = __builtin_amdgcn_cvt_pkrtz(b1_.x, b1_.y);                      \
    uB0.p[3] = __builtin_amdgcn_cvt_pkrtz(b1_.z, b1_.w);                      \
    uB1.p[0] = __builtin_amdgcn_cvt_pkrtz(b2_.x, b2_.y);                      \
    uB1.p[1] = __builtin_amdgcn_cvt_pkrtz(b2_.z, b2_.w);                      \
    uB1.p[2] = __builtin_amdgcn_cvt_pkrtz(b3_.x, b3_.y);                      \
    uB1.p[3] = __builtin_amdgcn_cvt_pkrtz(b3_.z, b3_.w);                      \
    *(h8*)&Als[bsel_][wof0] = uA0.v;                                          \
    *(h8*)&Als[bsel_][wof1] = uA1.v;                                          \
    *(h8*)&Bls[bsel_][wof0] = uB0.v;                                          \
    *(h8*)&Bls[bsel_][wof1] = uB1.v;                                          }

#define COMPUTE(bsel_) {                                                      \
    h8 afr[4], bfr[4];                                                        \
    _Pragma("unroll")                                                         \
    for (int m = 0; m < 4; ++m)                                               \
        afr[m] = *(const h8*)&Als[bsel_][lg * 1024 + (wr * 64 + m * 16 + l15) * 8]; \
    _Pragma("unroll")                                                         \
    for (int n = 0; n < 4; ++n)                                               \
        bfr[n] = *(const h8*)&Bls[bsel_][lg * 1024 + (wc * 64 + n * 16 + l15) * 8]; \
    _Pragma("unroll")                                                         \
    for (int m = 0; m < 4; ++m)                                               \
        _Pragma("unroll")                                                     \
        for (int n = 0; n < 4; ++n)                                           \
            acc[m][n] = __builtin_amdgcn_mfma_f32_16x16x32_f16(               \
                afr[m], bfr[n], acc[m][n], 0, 0, 0);                          }

    // prologue: tile 0 staged, tile 1 left for the loop
    LOADR(0);
    CVTWRITE(0);
    __syncthreads();

    #pragma unroll
    for (int s = 0; s < 15; ++s) {
        LOADR((s + 1) * BK);       // fp32 loads fly during COMPUTE
        COMPUTE(s & 1);
        CVTWRITE((s + 1) & 1);     // data-dep waits the loads here
        __syncthreads();           // ds_writes visible; VMEM queue empty
    }
    COMPUTE(1);                    // s = 15

    // epilogue: p = sum over this lane's 4 e's of w2*tanh(h + b1)
    float pp[4][4];
    #pragma unroll
    for (int m = 0; m < 4; ++m)
        #pragma unroll
        for (int i = 0; i < 4; ++i) {
            float p = 0.f;
            #pragma unroll
            for (int n = 0; n < 4; ++n)
                p += w2v[n] * fast_tanh(acc[m][n][i] + b1v[n]);
            pp[m][i] = p;
        }
    // reduce across the 16 e-lanes of each lane-group
    #pragma unroll
    for (int off = 1; off < 16; off <<= 1)
        #pragma unroll
        for (int m = 0; m < 4; ++m)
            #pragma unroll
            for (int i = 0; i < 4; ++i)
                pp[m][i] += __shfl_xor(pp[m][i], off);
    __syncthreads();
    if (l15 == 0) {
        #pragma unroll
        for (int m = 0; m < 4; ++m)
            #pragma unroll
            for (int i = 0; i < 4; ++i)
                sred[wc][wr * 64 + m * 16 + lg * 4 + i] = pp[m][i];
    }
    __syncthreads();
    if (tid < BM)
        spart[(long)be * BT + trow0 + tid] = sred[0][tid] + sred[1][tid];
}

// ---------------------------------------------------------------------------
// Kernel 2: chunk_sum. No global max needed (softmax shift-invariant; |s| is
// bounded by ||w2||_1 ~ 28 so exp(s) can't overflow fp32).
// Per (c,b) block: s[t] = sum_be spart[be][t] (written to ws for context),
// e[t] = exp(s[t]); csum[b,c,d] = sum_t e[t]*x[t,d]; esum[b,c] = sum_t e[t].
// ---------------------------------------------------------------------------
__global__ __launch_bounds__(128) void chunk_sum_kernel(
    const float* __restrict__ x, const float* __restrict__ spart,
    float* __restrict__ s_ws, float* __restrict__ csum,
    float* __restrict__ esum)
{
    __shared__ float el[CHUNK];
    __shared__ float wred[2];
    const int c = blockIdx.x, b = blockIdx.y;
    const int tid = threadIdx.x;
    const long bt = (long)b * TLEN + c * CHUNK + tid;

    float sv = spart[bt] + spart[BT + bt] + spart[2l * BT + bt] + spart[3l * BT + bt];
    s_ws[bt] = sv;
    float ev = __expf(sv);
    el[tid] = ev;
    // per-chunk e total: wave reduce (64) + 2-wave combine
    float r = ev;
    #pragma unroll
    for (int off = 1; off < 64; off <<= 1) r += __shfl_xor(r, off);
    if ((tid & 63) == 0) wred[tid >> 6] = r;
    __syncthreads();
    if (tid == 0) esum[b * NCHUNK + c] = wred[0] + wred[1];

    const float4* xb = (const float4*)(x + ((long)b * TLEN + c * CHUNK) * DIM);
    float4 acc = {0.f, 0.f, 0.f, 0.f};
    for (int t = 0; t < CHUNK; ++t) {
        float4 xv = xb[t * (DIM / 4) + tid];
        float wgt = el[t];
        acc.x += wgt * xv.x; acc.y += wgt * xv.y;
        acc.z += wgt * xv.z; acc.w += wgt * xv.w;
    }
    ((float4*)(csum + ((long)(b * NCHUNK + c)) * DIM))[tid] = acc;
}

// ---------------------------------------------------------------------------
// Kernel 3: chunk_scan. Per b: exclusive scan csum over c (512 lanes, tid<512)
// and exclusive scan esum over c (one wave, tid in [512,576), shfl scan).
// ---------------------------------------------------------------------------
__global__ __launch_bounds__(576) void chunk_scan_kernel(
    float* __restrict__ csum, float* __restrict__ esum)
{
    const int b = blockIdx.x;
    const int tid = threadIdx.x;
    if (tid < 512) {
        const int d = tid;
        float run = 0.f;
        #pragma unroll 8
        for (int c = 0; c < NCHUNK; ++c) {
            float* p = csum + ((long)(b * NCHUNK + c)) * DIM + d;
            float v = *p;
            *p = run;
            run += v;
        }
    } else {
        const int lane = tid - 512;          // 0..63 == chunk id
        float v = esum[b * NCHUNK + lane];
        const float own = v;
        #pragma unroll
        for (int off = 1; off < 64; off <<= 1) {
            float u = __shfl_up(v, off);
            if (lane >= off) v += u;
        }
        esum[b * NCHUNK + lane] = v - own;   // exclusive prefix
    }
}

// ---------------------------------------------------------------------------
// Kernel 4: context. Recompute e[t] from s (ws), carry running den from the
// chunk-exclusive esum; out[b,t,d] = (csum_excl + running num) / running den.
// ---------------------------------------------------------------------------
__global__ __launch_bounds__(128) void context_kernel(
    const float* __restrict__ x, const float* __restrict__ s_ws,
    const float* __restrict__ esum, const float* __restrict__ csum,
    float* __restrict__ out)
{
    __shared__ float el[CHUNK];
    const int c = blockIdx.x, b = blockIdx.y;
    const int tid = threadIdx.x;
    el[tid] = __expf(s_ws[(long)b * TLEN + c * CHUNK + tid]);
    __syncthreads();
    float dacc = esum[b * NCHUNK + c];       // exclusive den prefix
    const float4* xb = (const float4*)(x + ((long)b * TLEN + c * CHUNK) * DIM);
    float4* ob = (float4*)(out + ((long)b * TLEN + c * CHUNK) * DIM);
    float4 acc = ((const float4*)(csum + ((long)(b * NCHUNK + c)) * DIM))[tid];
    for (int t = 0; t < CHUNK; ++t) {
        float4 xv = xb[t * (DIM / 4) + tid];
        float wv = el[t];
        dacc += wv;
        acc.x += wv * xv.x; acc.y += wv * xv.y;
        acc.z += wv * xv.z; acc.w += wv * xv.w;
        float inv = __fdividef(1.0f, dacc);
        float4 o = {acc.x * inv, acc.y * inv, acc.z * inv, acc.w * inv};
        ob[t * (DIM / 4) + tid] = o;
    }
}

// ---------------------------------------------------------------------------
extern "C" void kernel_launch(void* const* d_in, const int* in_sizes, int n_in,
                              void* d_out, int out_size, void* d_ws, size_t ws_size,
                              hipStream_t stream)
{
    const float* x  = (const float*)d_in[0];   // [4,8192,512]
    const float* W1 = (const float*)d_in[1];   // [512,512] row-major [e][d]
    const float* b1 = (const float*)d_in[2];   // [512]
    const float* w2 = (const float*)d_in[3];   // [512]
    // d_in[4] = b2 scalar: softmax shift-invariant, unused.
    float* out = (float*)d_out;

    float* ws   = (float*)d_ws;
    float* s_ws = ws;                       // [32768]
    float* csum = ws + BT;                  // [4*64*512] = 131072
    float* esum = ws + BT + 4 * NCHUNK * DIM;   // [4*64]

    // spart scratch lives in d_out (67 MB) at a 48 MB offset: written by
    // score, read by chunk_sum, then overwritten by context's final output.
    float* spart = out + 12l * 1024 * 1024;     // [4][32768] floats

    score_mfma_kernel<<<(BT / BM) * 4, 256, 0, stream>>>(x, W1, b1, w2, spart);
    chunk_sum_kernel<<<dim3(NCHUNK, BATCH), 128, 0, stream>>>(x, spart, s_ws, csum, esum);
    chunk_scan_kernel<<<BATCH, 576, 0, stream>>>(csum, esum);
    context_kernel<<<dim3(NCHUNK, BATCH), 128, 0, stream>>>(x, s_ws, esum, csum, out);
}

// Round 8
// 86.329 us; speedup vs baseline: 1.0086x; 1.0086x over previous
//
#include <hip/hip_runtime.h>
#include <hip/hip_bf16.h>
#include <math.h>

// Problem constants
#define BATCH 4
#define TLEN 8192
#define BT 32768      // BATCH*TLEN
#define DIM 512
#define CHUNK 128     // t per scan chunk
#define NCHUNK 64     // TLEN / CHUNK

// score GEMM tile
#define BM 128
#define BN 128
#define BK 32

typedef _Float16 h8 __attribute__((ext_vector_type(8)));
typedef _Float16 h4 __attribute__((ext_vector_type(4)));
typedef float f4 __attribute__((ext_vector_type(4)));

__device__ __forceinline__ void gload_lds16(const _Float16* g, _Float16* l) {
    __builtin_amdgcn_global_load_lds(
        (const __attribute__((address_space(1))) void*)g,
        (__attribute__((address_space(3))) void*)l, 16, 0, 0);
}

// fast tanh: 1 - 2/(e^{2z}+1). |err| ~1e-6; saturates correctly at +-1.
__device__ __forceinline__ float fast_tanh(float z) {
    float u = __expf(2.0f * z);
    return 1.0f - __fdividef(2.0f, u + 1.0f);
}

// ---------------------------------------------------------------------------
// Kernel 0: convert x (fp32) and W1 (fp32) to fp16, packed into d_out scratch.
// ---------------------------------------------------------------------------
__global__ __launch_bounds__(256) void convert_kernel(
    const float* __restrict__ x, const float* __restrict__ W1,
    _Float16* __restrict__ hbuf)
{
    const long i = (long)blockIdx.x * 256 + threadIdx.x;   // float4 index
    const long XD4 = (long)BT * DIM / 4;
    const long total4 = XD4 + (long)DIM * DIM / 4;
    if (i >= total4) return;
    float4 v;
    if (i < XD4) v = ((const float4*)x)[i];
    else         v = ((const float4*)W1)[i - XD4];
    h4 o = { (_Float16)v.x, (_Float16)v.y, (_Float16)v.z, (_Float16)v.w };
    *(h4*)(hbuf + i * 4) = o;
}

// ---------------------------------------------------------------------------
// Kernel 1: score GEMM, counted-vmcnt pipeline, 3-buffer / 2-step prefetch.
// Per K-step: STAGE(s+2) -> vmcnt(8) -> barrier -> ds_read+MFMA(s) ->
// lgkmcnt(0) -> barrier.  vmcnt(8) waits only stage s (issued 2 steps ago,
// ~300+ cyc of lookahead); stages s+1, s+2 stay in flight.  WAR on buffer
// (s+2)%3 is sealed by step s-1's lgkmcnt(0)+barrier.
// ---------------------------------------------------------------------------
__global__ __launch_bounds__(256, 3) void score_mfma_kernel(
    const _Float16* __restrict__ xh, const _Float16* __restrict__ wh,
    const float* __restrict__ b1, const float* __restrict__ w2,
    float* __restrict__ spart)
{
    __shared__ _Float16 Als[3][BM * BK];   // 3 x 8 KB
    __shared__ _Float16 Bls[3][BM * BK];   // 3 x 8 KB
    __shared__ float sred[2][BM];          // 1 KB

    // bijective XCD-chunked swizzle over 1024 blocks (1024 % 8 == 0)
    const int orig = blockIdx.x;
    const int wid  = (orig & 7) * 128 + (orig >> 3);
    const int bt = wid >> 2, be = wid & 3;
    const long trow0 = (long)bt * BM;
    const int  ecol0 = be * BN;

    const int tid  = threadIdx.x;
    const int lane = tid & 63;
    const int w    = tid >> 6;       // 0..3
    const int wr   = w >> 1;         // t-half of tile
    const int wc   = w & 1;          // e-half of tile
    const int l15  = lane & 15;
    const int lg   = lane >> 4;      // 0..3

    // staging: wave w covers rows [w*32, w*32+32), 8 rows per 1KB issue pair.
    // source 16B-group = (lane&3) ^ (srow&3)  (involution; read applies same)
    const int srow = w * 32 + (lane >> 2);
    const int skof = ((lane & 3) ^ (srow & 3)) * 8;
    const _Float16* ga = xh + (trow0 + srow) * DIM + skof;
    const _Float16* gb = wh + (long)(ecol0 + srow) * DIM + skof;

    // frag-read swizzled k-offset: constant per lane (row&3 == l15&3)
    const int koff = (lg ^ (l15 & 3)) * 8;

    // preload epilogue operands BEFORE the pipeline so loop vmcnt is exact
    float b1v[4], w2v[4];
    #pragma unroll
    for (int n = 0; n < 4; ++n) {
        int e = ecol0 + wc * 64 + n * 16 + l15;
        b1v[n] = b1[e];
        w2v[n] = w2[e];
    }
    asm volatile("s_waitcnt vmcnt(0)" ::: "memory");

    f4 acc[4][4];
    #pragma unroll
    for (int m = 0; m < 4; ++m)
        #pragma unroll
        for (int n = 0; n < 4; ++n) acc[m][n] = (f4){0.f, 0.f, 0.f, 0.f};

#define STAGE(buf_, k0_) {                                        \
    _Float16* lA_ = &Als[buf_][w * 1024];                         \
    _Float16* lB_ = &Bls[buf_][w * 1024];                         \
    gload_lds16(ga + (k0_),            lA_);                      \
    gload_lds16(ga + 16 * DIM + (k0_), lA_ + 512);                \
    gload_lds16(gb + (k0_),            lB_);                      \
    gload_lds16(gb + 16 * DIM + (k0_), lB_ + 512);                }

#define COMPUTE(bsel_) {                                                      \
    h8 afr[4], bfr[4];                                                        \
    _Pragma("unroll")                                                         \
    for (int m = 0; m < 4; ++m)                                               \
        afr[m] = *(const h8*)&Als[bsel_][(wr * 64 + m * 16 + l15) * BK + koff]; \
    _Pragma("unroll")                                                         \
    for (int n = 0; n < 4; ++n)                                               \
        bfr[n] = *(const h8*)&Bls[bsel_][(wc * 64 + n * 16 + l15) * BK + koff]; \
    _Pragma("unroll")                                                         \
    for (int m = 0; m < 4; ++m)                                               \
        _Pragma("unroll")                                                     \
        for (int n = 0; n < 4; ++n)                                           \
            acc[m][n] = __builtin_amdgcn_mfma_f32_16x16x32_f16(               \
                afr[m], bfr[n], acc[m][n], 0, 0, 0);                          }

    STAGE(0, 0 * BK);                              // stage 0 in flight (4)
    STAGE(1, 1 * BK);                              // stage 1 in flight (8)
    #pragma unroll
    for (int s = 0; s < 14; ++s) {
        STAGE((s + 2) % 3, (s + 2) * BK);          // 12 outstanding
        asm volatile("s_waitcnt vmcnt(8)" ::: "memory");   // stage s landed
        __builtin_amdgcn_s_barrier();
        COMPUTE(s % 3);
        asm volatile("s_waitcnt lgkmcnt(0)" ::: "memory"); // reads done
        __builtin_amdgcn_s_barrier();              // buf (s+3)%3 restageable
    }
    asm volatile("s_waitcnt vmcnt(4)" ::: "memory");       // stage 14 landed
    __builtin_amdgcn_s_barrier();
    COMPUTE(2);                                    // s = 14 -> buf 2
    asm volatile("s_waitcnt lgkmcnt(0)" ::: "memory");
    __builtin_amdgcn_s_barrier();
    asm volatile("s_waitcnt vmcnt(0)" ::: "memory");       // stage 15 landed
    __builtin_amdgcn_s_barrier();
    COMPUTE(0);                                    // s = 15 -> buf 0

    // epilogue: p = sum over this lane's 4 e's of w2*tanh(h + b1)
    float pp[4][4];
    #pragma unroll
    for (int m = 0; m < 4; ++m)
        #pragma unroll
        for (int i = 0; i < 4; ++i) {
            float p = 0.f;
            #pragma unroll
            for (int n = 0; n < 4; ++n)
                p += w2v[n] * fast_tanh(acc[m][n][i] + b1v[n]);
            pp[m][i] = p;
        }
    // reduce across the 16 e-lanes of each lane-group
    #pragma unroll
    for (int off = 1; off < 16; off <<= 1)
        #pragma unroll
        for (int m = 0; m < 4; ++m)
            #pragma unroll
            for (int i = 0; i < 4; ++i)
                pp[m][i] += __shfl_xor(pp[m][i], off);
    __syncthreads();
    if (l15 == 0) {
        #pragma unroll
        for (int m = 0; m < 4; ++m)
            #pragma unroll
            for (int i = 0; i < 4; ++i)
                sred[wc][wr * 64 + m * 16 + lg * 4 + i] = pp[m][i];
    }
    __syncthreads();
    if (tid < BM)
        spart[(long)be * BT + trow0 + tid] = sred[0][tid] + sred[1][tid];
}

// ---------------------------------------------------------------------------
// Kernel 2: chunk_sum. No global max needed (softmax shift-invariant; |s| is
// bounded by ||w2||_1 ~ 28 so exp(s) can't overflow fp32).
// Per (c,b) block: s[t] = sum_be spart[be][t] (written to ws for context),
// e[t] = exp(s[t]); csum[b,c,d] = sum_t e[t]*xh[t,d]; esum[b,c] = sum_t e[t].
// ---------------------------------------------------------------------------
__global__ __launch_bounds__(128) void chunk_sum_kernel(
    const _Float16* __restrict__ xh, const float* __restrict__ spart,
    float* __restrict__ s_ws, float* __restrict__ csum,
    float* __restrict__ esum)
{
    __shared__ float el[CHUNK];
    __shared__ float wred[2];
    const int c = blockIdx.x, b = blockIdx.y;
    const int tid = threadIdx.x;
    const long bt = (long)b * TLEN + c * CHUNK + tid;

    float sv = spart[bt] + spart[BT + bt] + spart[2l * BT + bt] + spart[3l * BT + bt];
    s_ws[bt] = sv;
    float ev = __expf(sv);
    el[tid] = ev;
    // per-chunk e total: wave reduce (64) + 2-wave combine
    float r = ev;
    #pragma unroll
    for (int off = 1; off < 64; off <<= 1) r += __shfl_xor(r, off);
    if ((tid & 63) == 0) wred[tid >> 6] = r;
    __syncthreads();
    if (tid == 0) esum[b * NCHUNK + c] = wred[0] + wred[1];

    const _Float16* xb = xh + ((long)b * TLEN + c * CHUNK) * DIM;
    float a0 = 0.f, a1 = 0.f, a2 = 0.f, a3 = 0.f;
    for (int t = 0; t < CHUNK; ++t) {
        h4 xv = *(const h4*)(xb + (long)t * DIM + tid * 4);
        float wgt = el[t];
        a0 += wgt * (float)xv[0];
        a1 += wgt * (float)xv[1];
        a2 += wgt * (float)xv[2];
        a3 += wgt * (float)xv[3];
    }
    float4 o = {a0, a1, a2, a3};
    ((float4*)(csum + ((long)(b * NCHUNK + c)) * DIM))[tid] = o;
}

// ---------------------------------------------------------------------------
// Kernel 3: chunk_scan. Per b: exclusive scan csum over c (512 lanes, tid<512)
// and exclusive scan esum over c (one wave, tid in [512,576), shfl scan).
// ---------------------------------------------------------------------------
__global__ __launch_bounds__(576) void chunk_scan_kernel(
    float* __restrict__ csum, float* __restrict__ esum)
{
    const int b = blockIdx.x;
    const int tid = threadIdx.x;
    if (tid < 512) {
        const int d = tid;
        float run = 0.f;
        #pragma unroll 8
        for (int c = 0; c < NCHUNK; ++c) {
            float* p = csum + ((long)(b * NCHUNK + c)) * DIM + d;
            float v = *p;
            *p = run;
            run += v;
        }
    } else {
        const int lane = tid - 512;          // 0..63 == chunk id
        float v = esum[b * NCHUNK + lane];
        const float own = v;
        #pragma unroll
        for (int off = 1; off < 64; off <<= 1) {
            float u = __shfl_up(v, off);
            if (lane >= off) v += u;
        }
        esum[b * NCHUNK + lane] = v - own;   // exclusive prefix
    }
}

// ---------------------------------------------------------------------------
// Kernel 4: context. Recompute e[t] from s (ws), carry running den from the
// chunk-exclusive esum; out[b,t,d] = (csum_excl + running num) / running den.
// ---------------------------------------------------------------------------
__global__ __launch_bounds__(128) void context_kernel(
    const float* __restrict__ x, const float* __restrict__ s_ws,
    const float* __restrict__ esum, const float* __restrict__ csum,
    float* __restrict__ out)
{
    __shared__ float el[CHUNK];
    const int c = blockIdx.x, b = blockIdx.y;
    const int tid = threadIdx.x;
    el[tid] = __expf(s_ws[(long)b * TLEN + c * CHUNK + tid]);
    __syncthreads();
    float dacc = esum[b * NCHUNK + c];       // exclusive den prefix
    const float4* xb = (const float4*)(x + ((long)b * TLEN + c * CHUNK) * DIM);
    float4* ob = (float4*)(out + ((long)b * TLEN + c * CHUNK) * DIM);
    float4 acc = ((const float4*)(csum + ((long)(b * NCHUNK + c)) * DIM))[tid];
    for (int t = 0; t < CHUNK; ++t) {
        float4 xv = xb[t * (DIM / 4) + tid];
        float wv = el[t];
        dacc += wv;
        acc.x += wv * xv.x; acc.y += wv * xv.y;
        acc.z += wv * xv.z; acc.w += wv * xv.w;
        float inv = __fdividef(1.0f, dacc);
        float4 o = {acc.x * inv, acc.y * inv, acc.z * inv, acc.w * inv};
        ob[t * (DIM / 4) + tid] = o;
    }
}

// ---------------------------------------------------------------------------
extern "C" void kernel_launch(void* const* d_in, const int* in_sizes, int n_in,
                              void* d_out, int out_size, void* d_ws, size_t ws_size,
                              hipStream_t stream)
{
    const float* x  = (const float*)d_in[0];   // [4,8192,512]
    const float* W1 = (const float*)d_in[1];   // [512,512] row-major [e][d]
    const float* b1 = (const float*)d_in[2];   // [512]
    const float* w2 = (const float*)d_in[3];   // [512]
    // d_in[4] = b2 scalar: softmax shift-invariant, unused.
    float* out = (float*)d_out;

    float* ws   = (float*)d_ws;
    float* s_ws = ws;                       // [32768]
    float* csum = ws + BT;                  // [4*64*512] = 131072
    float* esum = ws + BT + 4 * NCHUNK * DIM;   // [4*64]

    // fp16 operands + spart live in d_out (67 MB): all consumed before the
    // final context_kernel overwrites d_out with the real output.
    _Float16* hbuf = (_Float16*)d_out;
    const _Float16* xh = hbuf;                              // 16.7M halfs
    const _Float16* wh = hbuf + (long)BT * DIM;             // 262K halfs
    float* spart = (float*)(hbuf + (long)BT * DIM + DIM * DIM);  // [4][32768]

    const long total4 = ((long)BT * DIM + (long)DIM * DIM) / 4;
    const int convBlocks = (int)((total4 + 255) / 256);

    convert_kernel<<<convBlocks, 256, 0, stream>>>(x, W1, hbuf);
    score_mfma_kernel<<<(BT / BM) * 4, 256, 0, stream>>>(xh, wh, b1, w2, spart);
    chunk_sum_kernel<<<dim3(NCHUNK, BATCH), 128, 0, stream>>>(xh, spart, s_ws, csum, esum);
    chunk_scan_kernel<<<BATCH, 576, 0, stream>>>(csum, esum);
    context_kernel<<<dim3(NCHUNK, BATCH), 128, 0, stream>>>(x, s_ws, esum, csum, out);
}